// Round 1
// 1231.416 us; speedup vs baseline: 1.3164x; 1.3164x over previous
//
#include <hip/hip_runtime.h>

typedef __bf16 bf16_t;
typedef __attribute__((ext_vector_type(8))) __bf16 bf16x8;
typedef __attribute__((ext_vector_type(4))) float f32x4;

#define DMODEL 512
#define SEQ 200
#define NHEAD 8
#define DH 64
#define BTOT 512
#define QKVW 1536                  // fused q|k|v width

__device__ __forceinline__ float wave_sum(float v) {
#pragma unroll
    for (int m = 32; m >= 1; m >>= 1) v += __shfl_xor(v, m);
    return v;
}

// dual-dtype load/store: external tensors may be fp32 or bf16; flag decides.
__device__ __forceinline__ void load8f(const void* p, size_t off, int f32, float x[8]) {
    if (f32) {
        const f32x4* q = (const f32x4*)((const float*)p + off);
        f32x4 a = q[0], b = q[1];
#pragma unroll
        for (int j = 0; j < 4; ++j) { x[j] = a[j]; x[4 + j] = b[j]; }
    } else {
        bf16x8 u = *(const bf16x8*)((const bf16_t*)p + off);
#pragma unroll
        for (int j = 0; j < 8; ++j) x[j] = (float)u[j];
    }
}
__device__ __forceinline__ void store8f(void* p, size_t off, int f32, const float x[8]) {
    if (f32) {
        f32x4 a, b;
#pragma unroll
        for (int j = 0; j < 4; ++j) { a[j] = x[j]; b[j] = x[4 + j]; }
        f32x4* q = (f32x4*)((float*)p + off);
        q[0] = a; q[1] = b;
    } else {
        bf16x8 u;
#pragma unroll
        for (int j = 0; j < 8; ++j) u[j] = (__bf16)x[j];
        *(bf16x8*)((bf16_t*)p + off) = u;
    }
}
__device__ __forceinline__ float load1f(const void* p, size_t off, int f32) {
    return f32 ? ((const float*)p)[off] : (float)((const bf16_t*)p)[off];
}

// async global->LDS, 16B per lane; LDS dest must be the wave-uniform base
// (HW writes base + lane*16), global src is per-lane.
__device__ __forceinline__ void gload16(const bf16_t* g, bf16_t* l) {
    __builtin_amdgcn_global_load_lds(
        (const __attribute__((address_space(1))) void*)g,
        (__attribute__((address_space(3))) void*)l,
        16, 0, 0);
}

// ---------- probe: read input_tensor AS bf16; garbage magnitudes => data is fp32 ----------
__global__ __launch_bounds__(256)
void probe_dtype(const void* p, int* flag)
{
    const bf16_t* b = (const bf16_t*)p;
    int tid = threadIdx.x;
    float mx = 0.f;
    for (int i = tid; i < 65536; i += 256) {
        float v = fabsf((float)b[i]);
        if (!(v == v)) v = 1e30f;           // NaN -> huge
        mx = fmaxf(mx, v);
    }
#pragma unroll
    for (int m = 32; m >= 1; m >>= 1) mx = fmaxf(mx, __shfl_xor(mx, m));
    __shared__ float wmax[4];
    int wave = tid >> 6, lane = tid & 63;
    if (lane == 0) wmax[wave] = mx;
    __syncthreads();
    if (tid == 0) {
        float m2 = fmaxf(fmaxf(wmax[0], wmax[1]), fmaxf(wmax[2], wmax[3]));
        *flag = (m2 > 1e3f) ? 1 : 0;        // bf16 N(0,1) maxes ~6; fp32-as-bf16 ~1e38
    }
}

// ---------- transpose four 512x512 weights -> bf16 WT[z][n][k] = W[z][k][n] ----------
// z order {Wq,Wk,Wv,Wd}: rows 0..1535 of WT are exactly the fused QKV B^T.
__global__ __launch_bounds__(256)
void transpose_w(const void* w0, const void* w1, const void* w2, const void* w3,
                 bf16_t* __restrict__ wt, const int* flagp)
{
    int f32 = *flagp;
    __shared__ bf16_t tile[32][33];
    const void* srcs[4] = {w0, w1, w2, w3};
    const void* src = srcs[blockIdx.z];
    bf16_t* dst = wt + (size_t)blockIdx.z * DMODEL * DMODEL;
    int tx = threadIdx.x, ty = threadIdx.y;   // block (32,8)
    int bx = blockIdx.x * 32, by = blockIdx.y * 32;
#pragma unroll
    for (int i = 0; i < 32; i += 8)
        tile[ty + i][tx] = (__bf16)load1f(src, (size_t)(by + ty + i) * DMODEL + bx + tx, f32);
    __syncthreads();
#pragma unroll
    for (int i = 0; i < 32; i += 8)
        dst[(size_t)(bx + ty + i) * DMODEL + by + tx] = tile[tx][ty + i];
}

// ---------- h = LayerNorm(input + pos) * g + beta ; external-dtype in, bf16 out ----------
__global__ __launch_bounds__(256)
void addln_in(const void* a, const void* c, const void* g, const void* beta,
              bf16_t* __restrict__ out, size_t base, const int* flagp)
{
    int f32 = *flagp;
    int wave = threadIdx.x >> 6, lane = threadIdx.x & 63;
    size_t row = (size_t)blockIdx.x * 4 + wave;
    size_t off = base + row * DMODEL + (size_t)lane * 8;
    float xa[8], xc[8];
    load8f(a, off, f32, xa);
    load8f(c, off, f32, xc);
    float x[8]; float s = 0.f, ss = 0.f;
#pragma unroll
    for (int j = 0; j < 8; ++j) {
        x[j] = xa[j] + xc[j];
        s += x[j]; ss += x[j] * x[j];
    }
    s = wave_sum(s); ss = wave_sum(ss);
    float mu = s * (1.f / DMODEL);
    float var = ss * (1.f / DMODEL) - mu * mu;
    float rstd = rsqrtf(var + 1e-12f);
    float vg[8], vb[8];
    load8f(g,    (size_t)lane * 8, f32, vg);
    load8f(beta, (size_t)lane * 8, f32, vb);
    bf16x8 o;
#pragma unroll
    for (int j = 0; j < 8; ++j)
        o[j] = (__bf16)((x[j] - mu) * rstd * vg[j] + vb[j]);
    *(bf16x8*)(out + row * DMODEL + (size_t)lane * 8) = o;
}

// ---------- out_final = LayerNorm(a + c) * g + beta ; bf16 in (strided), ext-dtype out ----------
__global__ __launch_bounds__(256)
void addln_out(const bf16_t* __restrict__ a, int lda, const bf16_t* __restrict__ c, int ldc2,
               const void* g, const void* beta, void* out, size_t obase,
               const int* flagp)
{
    int f32 = *flagp;
    int wave = threadIdx.x >> 6, lane = threadIdx.x & 63;
    size_t row = (size_t)blockIdx.x * 4 + wave;
    bf16x8 va = *(const bf16x8*)(a + row * (size_t)lda  + (size_t)lane * 8);
    bf16x8 vc = *(const bf16x8*)(c + row * (size_t)ldc2 + (size_t)lane * 8);
    float x[8]; float s = 0.f, ss = 0.f;
#pragma unroll
    for (int j = 0; j < 8; ++j) {
        x[j] = (float)va[j] + (float)vc[j];
        s += x[j]; ss += x[j] * x[j];
    }
    s = wave_sum(s); ss = wave_sum(ss);
    float mu = s * (1.f / DMODEL);
    float var = ss * (1.f / DMODEL) - mu * mu;
    float rstd = rsqrtf(var + 1e-12f);
    float vg[8], vb[8];
    load8f(g,    (size_t)lane * 8, f32, vg);
    load8f(beta, (size_t)lane * 8, f32, vb);
    float o[8];
#pragma unroll
    for (int j = 0; j < 8; ++j)
        o[j] = (x[j] - mu) * rstd * vg[j] + vb[j];
    store8f(out, obase + row * DMODEL + (size_t)lane * 8, f32, o);
}

// ---------- C[M,*] = A[M,K](lda) @ BT[*,K]^T + bias ; m97-style global_load_lds staging.
// elun=1: cols [0,1024) get ELU + per-head(64) L2-norm fused in the epilogue
// (a wave's 64-col window == one head; row's head elems live in 16 lanes x 4 regs). ----------
__global__ __launch_bounds__(256)
void gemm_fused(const bf16_t* A, int lda,
                const bf16_t* __restrict__ BT,
                const void* b0, const void* b1, const void* b2,
                bf16_t* C, int ldc,
                int K, int elun, const int* flagp)
{
    int f32 = *flagp;
    __shared__ alignas(16) bf16_t As[128][32];   // linear, unpadded: global_load_lds dest
    __shared__ alignas(16) bf16_t Bs[128][32];
    int tid = threadIdx.x;
    int wave = tid >> 6, lane = tid & 63, lm = lane & 15, quad = lane >> 4;
    int m0 = blockIdx.y * 128, n0 = blockIdx.x * 128;
    int wm = (wave >> 1) * 64, wn = (wave & 1) * 64;
    int r0 = tid >> 2, c0 = (tid & 3) * 8;       // lane-order matches linear LDS layout

    const bf16_t* ga = A  + (size_t)(m0 + r0) * lda + c0;
    const bf16_t* gb = BT + (size_t)(n0 + r0) * K   + c0;
    bf16_t* lasa = &As[0][0] + wave * 512;       // wave-uniform LDS bases (bytes: wave*1024)
    bf16_t* lasb = &Bs[0][0] + wave * 512;

    f32x4 zero = {0.f, 0.f, 0.f, 0.f};
    f32x4 acc[4][4];
#pragma unroll
    for (int i = 0; i < 4; ++i)
#pragma unroll
        for (int j = 0; j < 4; ++j) acc[i][j] = zero;

    for (int k0 = 0; k0 < K; k0 += 32) {
        __syncthreads();                          // prev iter's ds_reads done
        gload16(ga + k0,                      lasa);
        gload16(ga + k0 + (size_t)64 * lda,   lasa + 2048);
        gload16(gb + k0,                      lasb);
        gload16(gb + k0 + (size_t)64 * K,     lasb + 2048);
        __syncthreads();                          // drains vmcnt -> tiles ready
        bf16x8 af[4], bfr[4];
#pragma unroll
        for (int i = 0; i < 4; ++i) af[i]  = *(const bf16x8*)&As[wm + i * 16 + lm][quad * 8];
#pragma unroll
        for (int j = 0; j < 4; ++j) bfr[j] = *(const bf16x8*)&Bs[wn + j * 16 + lm][quad * 8];
#pragma unroll
        for (int i = 0; i < 4; ++i)
#pragma unroll
            for (int j = 0; j < 4; ++j)
                acc[i][j] = __builtin_amdgcn_mfma_f32_16x16x32_bf16(af[i], bfr[j], acc[i][j], 0, 0, 0);
    }

    // --- epilogue: bias (+ optional ELU + per-head L2 norm), store ---
    const void* bp = b0;
    if (elun) { if (n0 >= 1024) bp = b2; else if (n0 >= 512) bp = b1; }
    float bvv[4];
#pragma unroll
    for (int j = 0; j < 4; ++j)
        bvv[j] = load1f(bp, (size_t)((n0 + wn + j * 16 + lm) & (DMODEL - 1)), f32);
#pragma unroll
    for (int i = 0; i < 4; ++i)
#pragma unroll
        for (int j = 0; j < 4; ++j)
#pragma unroll
            for (int r = 0; r < 4; ++r) acc[i][j][r] += bvv[j];

    if (elun && n0 < 1024) {                      // q/k segments: ELU + L2 norm over head(64)
#pragma unroll
        for (int i = 0; i < 4; ++i)
#pragma unroll
            for (int r = 0; r < 4; ++r) {
                float e[4]; float ss = 0.f;
#pragma unroll
                for (int j = 0; j < 4; ++j) {
                    float v = acc[i][j][r];
                    float t = v > 0.f ? v : expm1f(v);
                    e[j] = t; ss += t * t;
                }
                ss += __shfl_xor(ss, 1); ss += __shfl_xor(ss, 2);
                ss += __shfl_xor(ss, 4); ss += __shfl_xor(ss, 8);   // 16 lanes of one quad = one row
                float rs = rsqrtf(ss);
#pragma unroll
                for (int j = 0; j < 4; ++j) acc[i][j][r] = e[j] * rs;
            }
    }
#pragma unroll
    for (int j = 0; j < 4; ++j) {
        int col = n0 + wn + j * 16 + lm;
#pragma unroll
        for (int i = 0; i < 4; ++i)
#pragma unroll
            for (int r = 0; r < 4; ++r) {
                int row = m0 + wm + i * 16 + quad * 4 + r;
                C[(size_t)row * ldc + col] = (__bf16)acc[i][j][r];
            }
    }
}

// ---------- fused kv + ctx per (b,h): kv[d][e]=sum_s kn[s,d] v[s,e] (LDS-resident),
// ctx[s][e]=(1/8) sum_d qn[s,d] kv[d,e], written IN PLACE into the q region. ----------
__global__ __launch_bounds__(256)
void kvctx_kernel(bf16_t* qkv)
{
    __shared__ alignas(16) bf16_t knT[64][232];   // [d][s], s zero-padded to 224
    __shared__ alignas(16) bf16_t vT [64][232];   // [e][s]
    int bh = blockIdx.x; int b = bh >> 3, h = bh & 7;
    int tid = threadIdx.x;
    size_t base = (size_t)b * SEQ * QKVW + (size_t)h * DH;
    const bf16_t* kp = qkv + base + 512;
    const bf16_t* vp = qkv + base + 1024;
    for (int idx = tid; idx < SEQ * DH; idx += 256) {
        int s = idx >> 6, d = idx & 63;
        knT[d][s] = kp[(size_t)s * QKVW + d];
        vT [d][s] = vp[(size_t)s * QKVW + d];
    }
    for (int idx = tid; idx < 64 * 32; idx += 256) {
        int d = idx >> 5, s = SEQ + (idx & 31);
        knT[d][s] = (__bf16)0.f;
        vT [d][s] = (__bf16)0.f;
    }
    __syncthreads();
    int wave = tid >> 6, lane = tid & 63, lm = lane & 15, quad = lane >> 4;
    int dbase = wave * 16;
    f32x4 zero = {0.f, 0.f, 0.f, 0.f};
    f32x4 acc[4];
#pragma unroll
    for (int in = 0; in < 4; ++in) acc[in] = zero;
#pragma unroll
    for (int k0 = 0; k0 < 224; k0 += 32) {
        bf16x8 a = *(const bf16x8*)&knT[dbase + lm][k0 + quad * 8];
#pragma unroll
        for (int in = 0; in < 4; ++in) {
            bf16x8 bb = *(const bf16x8*)&vT[in * 16 + lm][k0 + quad * 8];
            acc[in] = __builtin_amdgcn_mfma_f32_16x16x32_bf16(a, bb, acc[in], 0, 0, 0);
        }
    }
    __syncthreads();                              // everyone done reading knT/vT
    bf16_t* kvs = &knT[0][0];                     // alias dead knT as kvT[e][d], stride 72 (pad)
#pragma unroll
    for (int in = 0; in < 4; ++in)
#pragma unroll
        for (int r = 0; r < 4; ++r)
            kvs[(size_t)(in * 16 + lm) * 72 + dbase + quad * 4 + r] = (__bf16)acc[in][r];
    __syncthreads();
    bf16x8 bfr[2][4];
#pragma unroll
    for (int ks = 0; ks < 2; ++ks)
#pragma unroll
        for (int in = 0; in < 4; ++in)
            bfr[ks][in] = *(const bf16x8*)&kvs[(size_t)(in * 16 + lm) * 72 + ks * 32 + quad * 8];
    bf16_t* qp = qkv + base;                      // q region: read qn, write ctx (same rows per wave)
    for (int mt = wave; mt < 13; mt += 4) {       // ceil(200/16)=13 tiles
        int m0 = mt * 16;
        int sA = m0 + lm; if (sA > SEQ - 1) sA = SEQ - 1;
        f32x4 a2[4];
#pragma unroll
        for (int in = 0; in < 4; ++in) a2[in] = zero;
#pragma unroll
        for (int ks = 0; ks < 2; ++ks) {
            bf16x8 a = *(const bf16x8*)&qp[(size_t)sA * QKVW + ks * 32 + quad * 8];
#pragma unroll
            for (int in = 0; in < 4; ++in)
                a2[in] = __builtin_amdgcn_mfma_f32_16x16x32_bf16(a, bfr[ks][in], a2[in], 0, 0, 0);
        }
#pragma unroll
        for (int in = 0; in < 4; ++in)
#pragma unroll
            for (int r = 0; r < 4; ++r) {
                int s = m0 + quad * 4 + r;
                if (s < SEQ)
                    qp[(size_t)s * QKVW + in * 16 + lm] = (__bf16)(a2[in][r] * 0.125f);
            }
    }
}

extern "C" void kernel_launch(void* const* d_in, const int* in_sizes, int n_in,
                              void* d_out, int out_size, void* d_ws, size_t ws_size,
                              hipStream_t stream)
{
    const void* input = d_in[0];
    const void* pos   = d_in[1];
    // d_in[2] = attention_mask (unused by LinMHA)
    const void* Wq = d_in[3];
    const void* bq = d_in[4];
    const void* Wk = d_in[5];
    const void* bk = d_in[6];
    const void* Wv = d_in[7];
    const void* bv = d_in[8];
    const void* Wd = d_in[9];
    const void* bd = d_in[10];
    const void* g  = d_in[11];
    const void* be = d_in[12];

    // ws layout: [flag int @0, 256B reserved] [WT 2MB] [h crows*512] [qkv crows*1536], bf16
    int chunkb = 64;
    {
        size_t base_need = 256 + (size_t)4 * DMODEL * DMODEL * 2;
        size_t per_b = (size_t)SEQ * (DMODEL + QKVW) * 2;      // h + qkv per batch
        if (ws_size >= base_need + (size_t)128 * per_b) chunkb = 128;  // still L3-resident
    }
    int nchunk = BTOT / chunkb;
    int crows = chunkb * SEQ;

    int* flag   = (int*)d_ws;
    bf16_t* WT  = (bf16_t*)((char*)d_ws + 256);
    bf16_t* h_c = WT  + (size_t)4 * DMODEL * DMODEL;
    bf16_t* qkv = h_c + (size_t)crows * DMODEL;

    probe_dtype<<<dim3(1), 256, 0, stream>>>(input, flag);
    transpose_w<<<dim3(16, 16, 4), dim3(32, 8), 0, stream>>>(Wq, Wk, Wv, Wd, WT, flag);

    for (int c = 0; c < nchunk; ++c) {
        size_t roff = (size_t)c * crows * DMODEL;
        addln_in<<<dim3(crows / 4), 256, 0, stream>>>(input, pos, g, be, h_c, roff, flag);
        // fused QKV: C = qkv[crows][1536], ELU+L2norm on q/k segments in epilogue
        gemm_fused<<<dim3(QKVW / 128, crows / 128), 256, 0, stream>>>(
            h_c, DMODEL, WT, bq, bk, bv, qkv, QKVW, DMODEL, 1, flag);
        // kv + ctx fused; ctx lands in the (dead) q region of qkv
        kvctx_kernel<<<dim3(chunkb * NHEAD), 256, 0, stream>>>(qkv);
        // out-proj: A = ctx (q region, lda=1536), C -> dead v region
        gemm_fused<<<dim3(DMODEL / 128, crows / 128), 256, 0, stream>>>(
            qkv, QKVW, WT + (size_t)3 * DMODEL * DMODEL, bd, bd, bd,
            qkv + 1024, QKVW, DMODEL, 0, flag);
        addln_out<<<dim3(crows / 4), 256, 0, stream>>>(
            qkv + 1024, QKVW, h_c, DMODEL, g, be, d_out, roff, flag);
    }
}

// Round 2
// 1165.735 us; speedup vs baseline: 1.3906x; 1.0563x over previous
//
#include <hip/hip_runtime.h>

typedef __bf16 bf16_t;
typedef __attribute__((ext_vector_type(8))) __bf16 bf16x8;
typedef __attribute__((ext_vector_type(4))) __bf16 bf16x4;
typedef __attribute__((ext_vector_type(4))) float f32x4;

#define DMODEL 512
#define SEQ 200
#define NHEAD 8
#define DH 64
#define BTOT 512
#define QKVW 1536                  // fused q|k|v width

__device__ __forceinline__ float wave_sum(float v) {
#pragma unroll
    for (int m = 32; m >= 1; m >>= 1) v += __shfl_xor(v, m);
    return v;
}

// dual-dtype load/store: external tensors may be fp32 or bf16; flag decides.
__device__ __forceinline__ void load8f(const void* p, size_t off, int f32, float x[8]) {
    if (f32) {
        const f32x4* q = (const f32x4*)((const float*)p + off);
        f32x4 a = q[0], b = q[1];
#pragma unroll
        for (int j = 0; j < 4; ++j) { x[j] = a[j]; x[4 + j] = b[j]; }
    } else {
        bf16x8 u = *(const bf16x8*)((const bf16_t*)p + off);
#pragma unroll
        for (int j = 0; j < 8; ++j) x[j] = (float)u[j];
    }
}
__device__ __forceinline__ void store8f(void* p, size_t off, int f32, const float x[8]) {
    if (f32) {
        f32x4 a, b;
#pragma unroll
        for (int j = 0; j < 4; ++j) { a[j] = x[j]; b[j] = x[4 + j]; }
        f32x4* q = (f32x4*)((float*)p + off);
        q[0] = a; q[1] = b;
    } else {
        bf16x8 u;
#pragma unroll
        for (int j = 0; j < 8; ++j) u[j] = (__bf16)x[j];
        *(bf16x8*)((bf16_t*)p + off) = u;
    }
}
__device__ __forceinline__ float load1f(const void* p, size_t off, int f32) {
    return f32 ? ((const float*)p)[off] : (float)((const bf16_t*)p)[off];
}

// async global->LDS, 16B per lane; LDS dest is wave-uniform base (HW: base+lane*16),
// global src is per-lane.
__device__ __forceinline__ void gload16(const bf16_t* g, bf16_t* l) {
    __builtin_amdgcn_global_load_lds(
        (const __attribute__((address_space(1))) void*)g,
        (__attribute__((address_space(3))) void*)l,
        16, 0, 0);
}

// weight-row permutation: logical col n stored at phys row perm(n) (within 64-groups)
// so that MFMA B-fragment j on lane lm holds logical col 4*lm+j  -> contiguous C-stores.
__device__ __forceinline__ int permrow(int n) {
    return (n & ~63) | ((n & 3) * 16) | ((n & 63) >> 2);
}

// ---------- probe: read input_tensor AS bf16; garbage magnitudes => data is fp32 ----------
__global__ __launch_bounds__(256)
void probe_dtype(const void* p, int* flag)
{
    const bf16_t* b = (const bf16_t*)p;
    int tid = threadIdx.x;
    float mx = 0.f;
    for (int i = tid; i < 65536; i += 256) {
        float v = fabsf((float)b[i]);
        if (!(v == v)) v = 1e30f;           // NaN -> huge
        mx = fmaxf(mx, v);
    }
#pragma unroll
    for (int m = 32; m >= 1; m >>= 1) mx = fmaxf(mx, __shfl_xor(mx, m));
    __shared__ float wmax[4];
    int wave = tid >> 6, lane = tid & 63;
    if (lane == 0) wmax[wave] = mx;
    __syncthreads();
    if (tid == 0) {
        float m2 = fmaxf(fmaxf(wmax[0], wmax[1]), fmaxf(wmax[2], wmax[3]));
        *flag = (m2 > 1e3f) ? 1 : 0;        // bf16 N(0,1) maxes ~6; fp32-as-bf16 ~1e38
    }
}

// ---------- transpose four 512x512 weights -> bf16 WT[z][perm(n)][k] = W[z][k][n] ----------
__global__ __launch_bounds__(256)
void transpose_w(const void* w0, const void* w1, const void* w2, const void* w3,
                 bf16_t* __restrict__ wt, const int* flagp)
{
    int f32 = *flagp;
    __shared__ bf16_t tile[32][33];
    const void* srcs[4] = {w0, w1, w2, w3};
    const void* src = srcs[blockIdx.z];
    bf16_t* dst = wt + (size_t)blockIdx.z * DMODEL * DMODEL;
    int tx = threadIdx.x, ty = threadIdx.y;   // block (32,8)
    int bx = blockIdx.x * 32, by = blockIdx.y * 32;
#pragma unroll
    for (int i = 0; i < 32; i += 8)
        tile[ty + i][tx] = (__bf16)load1f(src, (size_t)(by + ty + i) * DMODEL + bx + tx, f32);
    __syncthreads();
#pragma unroll
    for (int i = 0; i < 32; i += 8)
        dst[(size_t)permrow(bx + ty + i) * DMODEL + by + tx] = tile[tx][ty + i];
}

// ---------- dual LN kernel: blocks [0,nout) do LN(aprev) -> out (final);
//            blocks [nout, nout+nin) do LN(in+pos) -> hout (next chunk). ----------
__global__ __launch_bounds__(256)
void addln_dual(const bf16_t* __restrict__ aprev, const void* g, const void* beta,
                void* out, size_t obase,
                const void* in, const void* pos, bf16_t* __restrict__ hout, size_t ibase,
                int nout, const int* flagp)
{
    int f32 = *flagp;
    int wave = threadIdx.x >> 6, lane = threadIdx.x & 63;
    int bid = blockIdx.x;
    float x[8]; float s = 0.f, ss = 0.f;
    if (bid < nout) {
        size_t row = (size_t)bid * 4 + wave;
        bf16x8 va = *(const bf16x8*)(aprev + row * QKVW + (size_t)lane * 8);
#pragma unroll
        for (int j = 0; j < 8; ++j) { x[j] = (float)va[j]; s += x[j]; ss += x[j] * x[j]; }
        s = wave_sum(s); ss = wave_sum(ss);
        float mu = s * (1.f / DMODEL);
        float rstd = rsqrtf(ss * (1.f / DMODEL) - mu * mu + 1e-12f);
        float vg[8], vb[8];
        load8f(g,    (size_t)lane * 8, f32, vg);
        load8f(beta, (size_t)lane * 8, f32, vb);
        float o[8];
#pragma unroll
        for (int j = 0; j < 8; ++j) o[j] = (x[j] - mu) * rstd * vg[j] + vb[j];
        store8f(out, obase + row * DMODEL + (size_t)lane * 8, f32, o);
    } else {
        size_t row = (size_t)(bid - nout) * 4 + wave;
        size_t off = ibase + row * DMODEL + (size_t)lane * 8;
        float xa[8], xc[8];
        load8f(in,  off, f32, xa);
        load8f(pos, off, f32, xc);
#pragma unroll
        for (int j = 0; j < 8; ++j) { x[j] = xa[j] + xc[j]; s += x[j]; ss += x[j] * x[j]; }
        s = wave_sum(s); ss = wave_sum(ss);
        float mu = s * (1.f / DMODEL);
        float rstd = rsqrtf(ss * (1.f / DMODEL) - mu * mu + 1e-12f);
        float vg[8], vb[8];
        load8f(g,    (size_t)lane * 8, f32, vg);
        load8f(beta, (size_t)lane * 8, f32, vb);
        bf16x8 o;
#pragma unroll
        for (int j = 0; j < 8; ++j)
            o[j] = (__bf16)((x[j] - mu) * rstd * vg[j] + vb[j]);
        *(bf16x8*)(hout + row * DMODEL + (size_t)lane * 8) = o;
    }
}

// ---------- C[M,*] = A[M,K](lda) @ WT^T + bias ; BK=64, global_load_lds staging with
// both-sides XOR swizzle (x ^= (row&7)*8), XCD-chunked block swizzle, permuted-B
// vectorized bf16x4 C-store, optional residual add, optional fused ELU+head-L2-norm. ----------
__global__ __launch_bounds__(256)
void gemm_fused(const bf16_t* A, int lda,
                const bf16_t* __restrict__ BT,
                const void* b0, const void* b1, const void* b2,
                const bf16_t* __restrict__ resid, int ldr,
                bf16_t* C, int ldc,
                int K, int elun, const int* flagp)
{
    int f32 = *flagp;
    __shared__ alignas(16) bf16_t As[128][64];   // linear dest for global_load_lds
    __shared__ alignas(16) bf16_t Bs[128][64];
    int tid = threadIdx.x;
    int wave = tid >> 6, lane = tid & 63, lm = lane & 15, quad = lane >> 4;

    // XCD-aware bijective swizzle (all grids here have nwg % 8 == 0)
    int gx = gridDim.x;
    int nwg = gx * gridDim.y;
    int lin = blockIdx.y * gx + blockIdx.x;
    int nl = lin;
    if ((nwg & 7) == 0) nl = (lin & 7) * (nwg >> 3) + (lin >> 3);
    int m0 = (nl / gx) * 128, n0 = (nl % gx) * 128;

    int wm = (wave >> 1) * 64, wn = (wave & 1) * 64;

    // staging: lane covers row_l = lane>>3 (0..7), 8 elems at swizzled source col
    int row_l = lane >> 3;
    int colsw = ((lane & 7) * 8) ^ (row_l * 8);  // inverse-swizzled global col
    const bf16_t* gaw = A  + (size_t)(m0 + wave * 8 + row_l) * lda + colsw;
    const bf16_t* gbw = BT + (size_t)(n0 + wave * 8 + row_l) * K   + colsw;
    bf16_t* la = &As[0][0] + wave * 512;         // wave-uniform LDS bases
    bf16_t* lb = &Bs[0][0] + wave * 512;

    f32x4 zero = {0.f, 0.f, 0.f, 0.f};
    f32x4 acc[4][4];
#pragma unroll
    for (int i = 0; i < 4; ++i)
#pragma unroll
        for (int j = 0; j < 4; ++j) acc[i][j] = zero;

    int xsw = (lm & 7) * 8;                      // ds_read col XOR (row&7 == lm&7)
    for (int k0 = 0; k0 < K; k0 += 64) {
        __syncthreads();                          // prev iter's ds_reads done
#pragma unroll
        for (int q = 0; q < 4; ++q) {
            gload16(gaw + k0 + (size_t)(q * 32) * lda, la + q * 2048);
            gload16(gbw + k0 + (size_t)(q * 32) * K,   lb + q * 2048);
        }
        __syncthreads();                          // drains vmcnt -> tiles ready
#pragma unroll
        for (int kk = 0; kk < 2; ++kk) {
            int x = (kk * 32 + quad * 8) ^ xsw;
            bf16x8 af[4], bfr[4];
#pragma unroll
            for (int i = 0; i < 4; ++i) af[i]  = *(const bf16x8*)&As[wm + i * 16 + lm][x];
#pragma unroll
            for (int j = 0; j < 4; ++j) bfr[j] = *(const bf16x8*)&Bs[wn + j * 16 + lm][x];
#pragma unroll
            for (int i = 0; i < 4; ++i)
#pragma unroll
                for (int j = 0; j < 4; ++j)
                    acc[i][j] = __builtin_amdgcn_mfma_f32_16x16x32_bf16(af[i], bfr[j], acc[i][j], 0, 0, 0);
        }
    }

    // --- epilogue: bias (logical col = n0+wn+4*lm+j), optional ELU+L2norm, resid, store ---
    const void* bp = b0;
    if (elun) { if (n0 >= 1024) bp = b2; else if (n0 >= 512) bp = b1; }
    int cb = n0 + wn + 4 * lm;                   // logical col base for this lane
    float bvv[4];
#pragma unroll
    for (int j = 0; j < 4; ++j)
        bvv[j] = load1f(bp, (size_t)((cb + j) & (DMODEL - 1)), f32);
#pragma unroll
    for (int i = 0; i < 4; ++i)
#pragma unroll
        for (int j = 0; j < 4; ++j)
#pragma unroll
            for (int r = 0; r < 4; ++r) acc[i][j][r] += bvv[j];

    if (elun && n0 < 1024) {                      // q/k segments: ELU + L2 norm over head(64)
#pragma unroll
        for (int i = 0; i < 4; ++i)
#pragma unroll
            for (int r = 0; r < 4; ++r) {
                float e[4]; float ss = 0.f;
#pragma unroll
                for (int j = 0; j < 4; ++j) {
                    float v = acc[i][j][r];
                    float t = v > 0.f ? v : expm1f(v);
                    e[j] = t; ss += t * t;
                }
                ss += __shfl_xor(ss, 1); ss += __shfl_xor(ss, 2);
                ss += __shfl_xor(ss, 4); ss += __shfl_xor(ss, 8);   // 16 lanes = one row's head
                float rs = rsqrtf(ss);
#pragma unroll
                for (int j = 0; j < 4; ++j) acc[i][j][r] = e[j] * rs;
            }
    }
#pragma unroll
    for (int i = 0; i < 4; ++i)
#pragma unroll
        for (int r = 0; r < 4; ++r) {
            int row = m0 + wm + i * 16 + quad * 4 + r;
            float o[4];
            if (resid) {
                bf16x4 hv = *(const bf16x4*)&resid[(size_t)row * ldr + cb];
#pragma unroll
                for (int j = 0; j < 4; ++j) o[j] = acc[i][j][r] + (float)hv[j];
            } else {
#pragma unroll
                for (int j = 0; j < 4; ++j) o[j] = acc[i][j][r];
            }
            bf16x4 ov;
#pragma unroll
            for (int j = 0; j < 4; ++j) ov[j] = (__bf16)o[j];
            *(bf16x4*)&C[(size_t)row * ldc + cb] = ov;
        }
}

// ---------- fused kv + ctx per (b,h): kv[d][e]=sum_s kn[s,d] v[s,e] (LDS-resident),
// ctx[s][e]=(1/8) sum_d qn[s,d] kv[d,e], written IN PLACE into the q region. ----------
__global__ __launch_bounds__(256)
void kvctx_kernel(bf16_t* qkv)
{
    __shared__ alignas(16) bf16_t knT[64][232];   // [d][s], s zero-padded to 224
    __shared__ alignas(16) bf16_t vT [64][232];   // [e][s]
    int bh = blockIdx.x; int b = bh >> 3, h = bh & 7;
    int tid = threadIdx.x;
    size_t base = (size_t)b * SEQ * QKVW + (size_t)h * DH;
    const bf16_t* kp = qkv + base + 512;
    const bf16_t* vp = qkv + base + 1024;
    for (int idx = tid; idx < SEQ * DH; idx += 256) {
        int s = idx >> 6, d = idx & 63;
        knT[d][s] = kp[(size_t)s * QKVW + d];
        vT [d][s] = vp[(size_t)s * QKVW + d];
    }
    for (int idx = tid; idx < 64 * 32; idx += 256) {
        int d = idx >> 5, s = SEQ + (idx & 31);
        knT[d][s] = (__bf16)0.f;
        vT [d][s] = (__bf16)0.f;
    }
    __syncthreads();
    int wave = tid >> 6, lane = tid & 63, lm = lane & 15, quad = lane >> 4;
    int dbase = wave * 16;
    f32x4 zero = {0.f, 0.f, 0.f, 0.f};
    f32x4 acc[4];
#pragma unroll
    for (int in = 0; in < 4; ++in) acc[in] = zero;
#pragma unroll
    for (int k0 = 0; k0 < 224; k0 += 32) {
        bf16x8 a = *(const bf16x8*)&knT[dbase + lm][k0 + quad * 8];
#pragma unroll
        for (int in = 0; in < 4; ++in) {
            bf16x8 bb = *(const bf16x8*)&vT[in * 16 + lm][k0 + quad * 8];
            acc[in] = __builtin_amdgcn_mfma_f32_16x16x32_bf16(a, bb, acc[in], 0, 0, 0);
        }
    }
    __syncthreads();                              // everyone done reading knT/vT
    bf16_t* kvs = &knT[0][0];                     // alias dead knT as kvT[e][d], stride 72
#pragma unroll
    for (int in = 0; in < 4; ++in)
#pragma unroll
        for (int r = 0; r < 4; ++r)
            kvs[(size_t)(in * 16 + lm) * 72 + dbase + quad * 4 + r] = (__bf16)acc[in][r];
    __syncthreads();
    bf16x8 bfr[2][4];
#pragma unroll
    for (int ks = 0; ks < 2; ++ks)
#pragma unroll
        for (int in = 0; in < 4; ++in)
            bfr[ks][in] = *(const bf16x8*)&kvs[(size_t)(in * 16 + lm) * 72 + ks * 32 + quad * 8];
    bf16_t* qp = qkv + base;                      // q region: read qn, write ctx
    for (int mt = wave; mt < 13; mt += 4) {       // ceil(200/16)=13 tiles
        int m0 = mt * 16;
        int sA = m0 + lm; if (sA > SEQ - 1) sA = SEQ - 1;
        f32x4 a2[4];
#pragma unroll
        for (int in = 0; in < 4; ++in) a2[in] = zero;
#pragma unroll
        for (int ks = 0; ks < 2; ++ks) {
            bf16x8 a = *(const bf16x8*)&qp[(size_t)sA * QKVW + ks * 32 + quad * 8];
#pragma unroll
            for (int in = 0; in < 4; ++in)
                a2[in] = __builtin_amdgcn_mfma_f32_16x16x32_bf16(a, bfr[ks][in], a2[in], 0, 0, 0);
        }
#pragma unroll
        for (int in = 0; in < 4; ++in)
#pragma unroll
            for (int r = 0; r < 4; ++r) {
                int s = m0 + quad * 4 + r;
                if (s < SEQ)
                    qp[(size_t)s * QKVW + in * 16 + lm] = (__bf16)(a2[in][r] * 0.125f);
            }
    }
}

extern "C" void kernel_launch(void* const* d_in, const int* in_sizes, int n_in,
                              void* d_out, int out_size, void* d_ws, size_t ws_size,
                              hipStream_t stream)
{
    const void* input = d_in[0];
    const void* pos   = d_in[1];
    // d_in[2] = attention_mask (unused by LinMHA)
    const void* Wq = d_in[3];
    const void* bq = d_in[4];
    const void* Wk = d_in[5];
    const void* bk = d_in[6];
    const void* Wv = d_in[7];
    const void* bv = d_in[8];
    const void* Wd = d_in[9];
    const void* bd = d_in[10];
    const void* g  = d_in[11];
    const void* be = d_in[12];

    // ws layout: [flag int @0, 256B] [WT 2MB] [h crows*512] [qkv crows*1536], bf16
    int chunkb = 64;
    {
        size_t base_need = 256 + (size_t)4 * DMODEL * DMODEL * 2;
        size_t per_b = (size_t)SEQ * (DMODEL + QKVW) * 2;
        if (ws_size >= base_need + (size_t)128 * per_b) chunkb = 128;  // L3-resident
    }
    int nchunk = BTOT / chunkb;
    int crows = chunkb * SEQ;

    int* flag   = (int*)d_ws;
    bf16_t* WT  = (bf16_t*)((char*)d_ws + 256);
    bf16_t* h_c = WT  + (size_t)4 * DMODEL * DMODEL;
    bf16_t* qkv = h_c + (size_t)crows * DMODEL;

    probe_dtype<<<dim3(1), 256, 0, stream>>>(input, flag);
    transpose_w<<<dim3(16, 16, 4), dim3(32, 8), 0, stream>>>(Wq, Wk, Wv, Wd, WT, flag);

    // LN_in for chunk 0
    addln_dual<<<dim3(crows / 4), 256, 0, stream>>>(
        (const bf16_t*)qkv, g, be, d_out, 0, input, pos, h_c, 0, 0, flag);

    for (int c = 0; c < nchunk; ++c) {
        size_t roff = (size_t)c * crows * DMODEL;
        // fused QKV: C = qkv[crows][1536], ELU+L2norm on q/k segments in epilogue
        gemm_fused<<<dim3(QKVW / 128, crows / 128), 256, 0, stream>>>(
            h_c, DMODEL, WT, bq, bk, bv, nullptr, 0, qkv, QKVW, DMODEL, 1, flag);
        // kv + ctx fused; ctx lands in the (dead) q region of qkv
        kvctx_kernel<<<dim3(chunkb * NHEAD), 256, 0, stream>>>(qkv);
        // out-proj: A = ctx (q region, lda=1536), +h residual fused, C -> dead v region
        gemm_fused<<<dim3(DMODEL / 128, crows / 128), 256, 0, stream>>>(
            qkv, QKVW, WT + (size_t)3 * DMODEL * DMODEL, bd, bd, bd,
            h_c, DMODEL, qkv + 1024, QKVW, DMODEL, 0, flag);
        // LN_out(c) fused with LN_in(c+1)
        int nout = crows / 4;
        int nin = (c + 1 < nchunk) ? crows / 4 : 0;
        size_t ibase = (size_t)(c + 1) * crows * DMODEL;
        addln_dual<<<dim3(nout + nin), 256, 0, stream>>>(
            qkv + 1024, g, be, d_out, roff, input, pos, h_c, ibase, nout, flag);
    }
}